// Round 5
// baseline (290.884 us; speedup 1.0000x reference)
//
#include <hip/hip_runtime.h>

// DiceLoss: predict,target fp32 [B=2, O=4, D=64, H=256, W=256]
// out = mean over (b,o) of [ sum_d valid*(1 - 2*num/den) / sum_d valid ]
// num = sum_hw sigmoid(p)*t ; den = sum_hw sigmoid(p) + sum_hw t + 1
// valid = (t[b,o,d,0] != -1)
//
// R5 structure: m13-style flat streaming. Consecutive blocks read consecutive
// 4 KB pieces (one float4/thread), so the chip's instantaneous read window is
// a rolling contiguous ~8 MB -> uniform HBM channel coverage (fixes the
// 64/256 KB-strided partition camping that pinned R1-R4 at 2.7 TB/s).

constexpr int HW     = 256 * 256;   // 65536 elems per slice
constexpr int NSLICE = 2 * 4 * 64;  // 512
constexpr int NPAIR  = 2 * 4;       // 8 (b,o) pairs
constexpr int T      = 256;         // threads per block
constexpr int NBLK   = NSLICE * HW / (T * 4);  // 32768 blocks, 4 KB/array each
constexpr int BLOCKS_PER_SLICE = HW / (T * 4); // 64

// ws: [0..512) sum(p*t) | [512..1024) sum(p) | [1024..1536) sum(t)

__global__ __launch_bounds__(1024) void zero_ws(float* __restrict__ ws) {
    const int i = blockIdx.x * 1024 + threadIdx.x;
    if (i < 3 * NSLICE) ws[i] = 0.f;
}

__global__ __launch_bounds__(T) void dice_stage1(
    const float4* __restrict__ p4,
    const float4* __restrict__ t4,
    float* __restrict__ ws)
{
    const int idx = blockIdx.x * T + threadIdx.x;   // global float4 index
    const float4 pv = p4[idx];
    const float4 tv = t4[idx];

    const float e0 = 1.f / (1.f + __expf(-pv.x));
    const float e1 = 1.f / (1.f + __expf(-pv.y));
    const float e2 = 1.f / (1.f + __expf(-pv.z));
    const float e3 = 1.f / (1.f + __expf(-pv.w));

    float s_pt = (e0 * tv.x + e1 * tv.y) + (e2 * tv.z + e3 * tv.w);
    float s_p  = (e0 + e1) + (e2 + e3);
    float s_t  = (tv.x + tv.y) + (tv.z + tv.w);

    // 64-lane wave reduction
#pragma unroll
    for (int off = 32; off > 0; off >>= 1) {
        s_pt += __shfl_down(s_pt, off, 64);
        s_p  += __shfl_down(s_p,  off, 64);
        s_t  += __shfl_down(s_t,  off, 64);
    }

    __shared__ float l[3][T / 64];
    const int wave = threadIdx.x >> 6;
    const int lane = threadIdx.x & 63;
    if (lane == 0) { l[0][wave] = s_pt; l[1][wave] = s_p; l[2][wave] = s_t; }
    __syncthreads();

    // threads 0..2 each combine one value and issue one atomic
    if (threadIdx.x < 3) {
        float v = 0.f;
#pragma unroll
        for (int w = 0; w < T / 64; ++w) v += l[threadIdx.x][w];
        const int slice = blockIdx.x / BLOCKS_PER_SLICE;
        atomicAdd(&ws[threadIdx.x * NSLICE + slice], v);
    }
}

__global__ __launch_bounds__(NSLICE) void dice_stage2(
    const float* __restrict__ ws,
    const float* __restrict__ target,
    float* __restrict__ out)
{
    const int s = threadIdx.x;   // slice 0..511; wave w = (b,o) pair (D=64)
    const float num = ws[s];
    const float den = ws[NSLICE + s] + ws[2 * NSLICE + s] + 1.0f;  // SMOOTH=1
    const float dice  = 1.0f - 2.0f * num / den;
    const float valid = (target[(size_t)s * HW] != -1.0f) ? 1.0f : 0.0f;

    float dv = dice * valid;
    float v  = valid;
#pragma unroll
    for (int off = 32; off > 0; off >>= 1) {
        dv += __shfl_down(dv, off, 64);
        v  += __shfl_down(v,  off, 64);
    }
    __shared__ float pair_avg[NPAIR];
    const int wave = s >> 6;
    const int lane = s & 63;
    if (lane == 0) pair_avg[wave] = dv / v;
    __syncthreads();
    if (s == 0) {
        float acc = 0.f;
#pragma unroll
        for (int w = 0; w < NPAIR; ++w) acc += pair_avg[w];
        out[0] = acc * (1.0f / NPAIR);
    }
}

extern "C" void kernel_launch(void* const* d_in, const int* in_sizes, int n_in,
                              void* d_out, int out_size, void* d_ws, size_t ws_size,
                              hipStream_t stream) {
    const float4* predict = (const float4*)d_in[0];
    const float4* target4 = (const float4*)d_in[1];
    const float*  target  = (const float*)d_in[1];
    float* ws  = (float*)d_ws;
    float* out = (float*)d_out;

    zero_ws    <<<2, 1024, 0, stream>>>(ws);
    dice_stage1<<<NBLK, T, 0, stream>>>(predict, target4, ws);
    dice_stage2<<<1, NSLICE, 0, stream>>>(ws, target, out);
}

// Round 6
// 280.234 us; speedup vs baseline: 1.0380x; 1.0380x over previous
//
#include <hip/hip_runtime.h>

// DiceLoss: predict,target fp32 [B=2, O=4, D=64, H=256, W=256]
// out = mean over (b,o) of [ sum_d valid*(1 - 2*num/den) / sum_d valid ]
// num = sum_hw sigmoid(p)*t ; den = sum_hw sigmoid(p) + sum_hw t + 1
// valid = (t[b,o,d,0] != -1)
//
// R6: identical to R3's chunked structure EXCEPT each block walks its 64 KB
// chunk starting at a block-dependent phase. Instantaneous global address
// spacing becomes 17*4KB (coprime to power-of-2 channel interleave) instead
// of the 64KB comb of R1-R4 -> uniform HBM/L3 channel coverage.

constexpr int HW     = 256 * 256;                  // 65536 elems per slice
constexpr int NSLICE = 2 * 4 * 64;                 // 512
constexpr int NPAIR  = 2 * 4;                      // 8 (b,o) pairs
constexpr int T      = 256;                        // threads per block
constexpr int CHUNKS_PER_SLICE = 4;
constexpr int NCHUNK = NSLICE * CHUNKS_PER_SLICE;  // 2048 blocks
constexpr int CHUNK_ELEMS = HW / CHUNKS_PER_SLICE; // 16384 floats (64 KB)
constexpr int NITER  = CHUNK_ELEMS / 4 / T;        // 16 float4 steps

// ws layout (SoA): ws[0..NCHUNK) = sum(p*t), ws[NCHUNK..2N) = sum(p), ws[2N..3N) = sum(t)

__global__ __launch_bounds__(T) void dice_stage1(
    const float* __restrict__ predict,
    const float* __restrict__ target,
    float* __restrict__ ws)
{
    const int chunk = blockIdx.x;
    const int tid   = threadIdx.x;
    const int phase = chunk & (NITER - 1);          // per-block start offset
    const size_t base = (size_t)chunk * CHUNK_ELEMS;
    const float4* __restrict__ p4 = (const float4*)(predict + base);
    const float4* __restrict__ t4 = (const float4*)(target + base);

    float s_pt0 = 0.f, s_pt1 = 0.f, s_p = 0.f, s_t = 0.f;

#pragma unroll
    for (int k = 0; k < NITER; ++k) {
        const int kk = (k + phase) & (NITER - 1);   // rotated walk
        const float4 pv = p4[kk * T + tid];
        const float4 tv = t4[kk * T + tid];
        const float e0 = 1.f / (1.f + __expf(-pv.x));
        const float e1 = 1.f / (1.f + __expf(-pv.y));
        const float e2 = 1.f / (1.f + __expf(-pv.z));
        const float e3 = 1.f / (1.f + __expf(-pv.w));
        s_pt0 += e0 * tv.x + e1 * tv.y;
        s_pt1 += e2 * tv.z + e3 * tv.w;
        s_p   += (e0 + e1) + (e2 + e3);
        s_t   += (tv.x + tv.y) + (tv.z + tv.w);
    }

    float s_pt = s_pt0 + s_pt1;

    // 64-lane wave reduction, then per-block LDS reduction
#pragma unroll
    for (int off = 32; off > 0; off >>= 1) {
        s_pt += __shfl_down(s_pt, off, 64);
        s_p  += __shfl_down(s_p,  off, 64);
        s_t  += __shfl_down(s_t,  off, 64);
    }

    __shared__ float l_pt[T / 64], l_p[T / 64], l_t[T / 64];
    const int wave = tid >> 6;
    const int lane = tid & 63;
    if (lane == 0) { l_pt[wave] = s_pt; l_p[wave] = s_p; l_t[wave] = s_t; }
    __syncthreads();

    if (tid == 0) {
        float a = 0.f, b = 0.f, c = 0.f;
#pragma unroll
        for (int w = 0; w < T / 64; ++w) { a += l_pt[w]; b += l_p[w]; c += l_t[w]; }
        ws[chunk]              = a;
        ws[NCHUNK + chunk]     = b;
        ws[2 * NCHUNK + chunk] = c;
    }
}

__global__ __launch_bounds__(NSLICE) void dice_stage2(
    const float* __restrict__ ws,
    const float* __restrict__ target,
    float* __restrict__ out)
{
    const int s = threadIdx.x;   // slice 0..511; wave w = (b,o) pair (D=64)
    float num = 0.f, sp = 0.f, st = 0.f;
#pragma unroll
    for (int c = 0; c < CHUNKS_PER_SLICE; ++c) {
        const int id = s * CHUNKS_PER_SLICE + c;
        num += ws[id];
        sp  += ws[NCHUNK + id];
        st  += ws[2 * NCHUNK + id];
    }
    const float den   = sp + st + 1.0f;              // SMOOTH = 1
    const float dice  = 1.0f - 2.0f * num / den;
    const float valid = (target[(size_t)s * HW] != -1.0f) ? 1.0f : 0.0f;

    float dv = dice * valid;
    float v  = valid;
#pragma unroll
    for (int off = 32; off > 0; off >>= 1) {
        dv += __shfl_down(dv, off, 64);
        v  += __shfl_down(v,  off, 64);
    }
    __shared__ float pair_avg[NPAIR];
    const int wave = s >> 6;
    const int lane = s & 63;
    if (lane == 0) pair_avg[wave] = dv / v;
    __syncthreads();
    if (s == 0) {
        float acc = 0.f;
#pragma unroll
        for (int w = 0; w < NPAIR; ++w) acc += pair_avg[w];
        out[0] = acc * (1.0f / NPAIR);
    }
}

extern "C" void kernel_launch(void* const* d_in, const int* in_sizes, int n_in,
                              void* d_out, int out_size, void* d_ws, size_t ws_size,
                              hipStream_t stream) {
    const float* predict = (const float*)d_in[0];
    const float* target  = (const float*)d_in[1];
    float* ws  = (float*)d_ws;
    float* out = (float*)d_out;

    dice_stage1<<<NCHUNK, T, 0, stream>>>(predict, target, ws);
    dice_stage2<<<1, NSLICE, 0, stream>>>(ws, target, out);
}

// Round 7
// 277.991 us; speedup vs baseline: 1.0464x; 1.0081x over previous
//
#include <hip/hip_runtime.h>

// DiceLoss: predict,target fp32 [B=2, O=4, D=64, H=256, W=256]
// out = mean over (b,o) of [ sum_d valid*(1 - 2*num/den) / sum_d valid ]
// num = sum_hw sigmoid(p)*t ; den = sum_hw sigmoid(p) + sum_hw t + 1
// valid = (t[b,o,d,0] != -1)
//
// R7: forced memory-level parallelism. R2/R3/R4 batching was silently undone
// by the MaxOccupancy scheduler (VGPR never exceeded 44 -> loads sunk to first
// use, ~2KB/wave in flight). Here the 16 global_load_dwordx4 of a batch are
// inline asm whose results are operand-tied to an asm s_waitcnt fence: the
// compiler MUST issue all 16 (16KB/wave) before any compute. The backend
// waitcnt pass does not track asm loads; the manual vmcnt(0) is the only wait.

typedef float f32x4 __attribute__((ext_vector_type(4)));

constexpr int HW     = 256 * 256;                  // 65536 elems per slice
constexpr int NSLICE = 2 * 4 * 64;                 // 512
constexpr int NPAIR  = 2 * 4;                      // 8 (b,o) pairs
constexpr int T      = 256;                        // threads per block
constexpr int CHUNKS_PER_SLICE = 4;
constexpr int NCHUNK = NSLICE * CHUNKS_PER_SLICE;  // 2048 blocks
constexpr int CHUNK_ELEMS = HW / CHUNKS_PER_SLICE; // 16384 floats (64 KB)
constexpr int NITER  = CHUNK_ELEMS / 4 / T;        // 16 float4 steps
constexpr int BATCH  = 8;                          // 8 (p,t) pairs = 16 loads in flight

// ws layout (SoA): ws[0..NCHUNK) = sum(p*t), ws[NCHUNK..2N) = sum(p), ws[2N..3N) = sum(t)

__global__ __launch_bounds__(T) void dice_stage1(
    const float* __restrict__ predict,
    const float* __restrict__ target,
    float* __restrict__ ws)
{
    const int chunk = blockIdx.x;
    const int tid   = threadIdx.x;
    const size_t base = (size_t)chunk * CHUNK_ELEMS;
    const f32x4* __restrict__ p4 = (const f32x4*)(predict + base);
    const f32x4* __restrict__ t4 = (const f32x4*)(target + base);

    float s_pt0 = 0.f, s_pt1 = 0.f, s_p = 0.f, s_t = 0.f;

#pragma unroll
    for (int k0 = 0; k0 < NITER; k0 += BATCH) {
        f32x4 pv[BATCH], tv[BATCH];
        // Issue all 16 loads; results only become usable after the fence.
#pragma unroll
        for (int j = 0; j < BATCH; ++j) {
            asm volatile("global_load_dwordx4 %0, %1, off"
                         : "=v"(pv[j])
                         : "v"(p4 + (k0 + j) * T + tid));
            asm volatile("global_load_dwordx4 %0, %1, off"
                         : "=v"(tv[j])
                         : "v"(t4 + (k0 + j) * T + tid));
        }
        // Fence: every loaded value is an operand, so no load can be sunk
        // below it and no use can be hoisted above it.
        asm volatile("s_waitcnt vmcnt(0)"
                     : "+v"(pv[0]), "+v"(pv[1]), "+v"(pv[2]), "+v"(pv[3]),
                       "+v"(pv[4]), "+v"(pv[5]), "+v"(pv[6]), "+v"(pv[7]),
                       "+v"(tv[0]), "+v"(tv[1]), "+v"(tv[2]), "+v"(tv[3]),
                       "+v"(tv[4]), "+v"(tv[5]), "+v"(tv[6]), "+v"(tv[7])
                     :
                     : "memory");
#pragma unroll
        for (int j = 0; j < BATCH; ++j) {
            const float e0 = 1.f / (1.f + __expf(-pv[j].x));
            const float e1 = 1.f / (1.f + __expf(-pv[j].y));
            const float e2 = 1.f / (1.f + __expf(-pv[j].z));
            const float e3 = 1.f / (1.f + __expf(-pv[j].w));
            s_pt0 += e0 * tv[j].x + e1 * tv[j].y;
            s_pt1 += e2 * tv[j].z + e3 * tv[j].w;
            s_p   += (e0 + e1) + (e2 + e3);
            s_t   += (tv[j].x + tv[j].y) + (tv[j].z + tv[j].w);
        }
    }

    float s_pt = s_pt0 + s_pt1;

    // 64-lane wave reduction, then per-block LDS reduction
#pragma unroll
    for (int off = 32; off > 0; off >>= 1) {
        s_pt += __shfl_down(s_pt, off, 64);
        s_p  += __shfl_down(s_p,  off, 64);
        s_t  += __shfl_down(s_t,  off, 64);
    }

    __shared__ float l_pt[T / 64], l_p[T / 64], l_t[T / 64];
    const int wave = tid >> 6;
    const int lane = tid & 63;
    if (lane == 0) { l_pt[wave] = s_pt; l_p[wave] = s_p; l_t[wave] = s_t; }
    __syncthreads();

    if (tid == 0) {
        float a = 0.f, b = 0.f, c = 0.f;
#pragma unroll
        for (int w = 0; w < T / 64; ++w) { a += l_pt[w]; b += l_p[w]; c += l_t[w]; }
        ws[chunk]              = a;
        ws[NCHUNK + chunk]     = b;
        ws[2 * NCHUNK + chunk] = c;
    }
}

__global__ __launch_bounds__(NSLICE) void dice_stage2(
    const float* __restrict__ ws,
    const float* __restrict__ target,
    float* __restrict__ out)
{
    const int s = threadIdx.x;   // slice 0..511; wave w = (b,o) pair (D=64)
    float num = 0.f, sp = 0.f, st = 0.f;
#pragma unroll
    for (int c = 0; c < CHUNKS_PER_SLICE; ++c) {
        const int id = s * CHUNKS_PER_SLICE + c;
        num += ws[id];
        sp  += ws[NCHUNK + id];
        st  += ws[2 * NCHUNK + id];
    }
    const float den   = sp + st + 1.0f;              // SMOOTH = 1
    const float dice  = 1.0f - 2.0f * num / den;
    const float valid = (target[(size_t)s * HW] != -1.0f) ? 1.0f : 0.0f;

    float dv = dice * valid;
    float v  = valid;
#pragma unroll
    for (int off = 32; off > 0; off >>= 1) {
        dv += __shfl_down(dv, off, 64);
        v  += __shfl_down(v,  off, 64);
    }
    __shared__ float pair_avg[NPAIR];
    const int wave = s >> 6;
    const int lane = s & 63;
    if (lane == 0) pair_avg[wave] = dv / v;
    __syncthreads();
    if (s == 0) {
        float acc = 0.f;
#pragma unroll
        for (int w = 0; w < NPAIR; ++w) acc += pair_avg[w];
        out[0] = acc * (1.0f / NPAIR);
    }
}

extern "C" void kernel_launch(void* const* d_in, const int* in_sizes, int n_in,
                              void* d_out, int out_size, void* d_ws, size_t ws_size,
                              hipStream_t stream) {
    const float* predict = (const float*)d_in[0];
    const float* target  = (const float*)d_in[1];
    float* ws  = (float*)d_ws;
    float* out = (float*)d_out;

    dice_stage1<<<NCHUNK, T, 0, stream>>>(predict, target, ws);
    dice_stage2<<<1, NSLICE, 0, stream>>>(ws, target, out);
}